// Round 1
// baseline (193.735 us; speedup 1.0000x reference)
//
#include <hip/hip_runtime.h>
#include <cstdint>
#include <cstddef>

typedef __attribute__((ext_vector_type(8))) _Float16 half8;
typedef __attribute__((ext_vector_type(4))) _Float16 half4;
typedef __attribute__((ext_vector_type(4))) float f32x4;

#define NB 2
#define NS 2048
#define ND 1024
#define NH 16
#define NHD 64
#define NM (NB * NS) /* 4096 */

// ---------------------------------------------------------------- converts
__global__ void cvt_f32_f16(const float* __restrict__ src,
                            _Float16* __restrict__ dst, int n8) {
  int i = blockIdx.x * 256 + threadIdx.x;
  if (i >= n8) return;
  const float4* s4 = (const float4*)src + (size_t)i * 2;
  float4 a = s4[0], b = s4[1];
  half8 h;
  h[0] = (_Float16)a.x; h[1] = (_Float16)a.y;
  h[2] = (_Float16)a.z; h[3] = (_Float16)a.w;
  h[4] = (_Float16)b.x; h[5] = (_Float16)b.y;
  h[6] = (_Float16)b.z; h[7] = (_Float16)b.w;
  *(half8*)(dst + (size_t)i * 8) = h;
}

// cos/sin tables: [s][j], j = freq index 0..31. angle = s * 10000^(-2j/64)
__global__ void rope_tables(float* __restrict__ cosT, float* __restrict__ sinT) {
  int t = blockIdx.x * 256 + threadIdx.x;  // 0..65535
  int s = t >> 5, j = t & 31;
  float inv = expf(-(float)(2 * j) * (9.210340371976184f / 64.0f)); // ln(10000)/64
  float ang = (float)s * inv;
  cosT[t] = cosf(ang);
  sinT[t] = sinf(ang);
}

// ---------------------------------------------------------------- GEMM core
// C[M][N] = A[M][K] @ B[N][K]^T, f16 inputs, f32 acc. 128x128 tile, BK=32.
// 4 waves (2x2), each owns a 64x64 sub-tile = 4x4 fragments of 16x16x32 MFMA.
__device__ __forceinline__ void gload_lds16(const void* g, void* lds) {
  __builtin_amdgcn_global_load_lds(
      (const __attribute__((address_space(1))) unsigned int*)g,
      (__attribute__((address_space(3))) unsigned int*)lds, 16, 0, 0);
}

__device__ __forceinline__ void gemm_mainloop(const _Float16* __restrict__ A,
                                              const _Float16* __restrict__ Bw,
                                              _Float16* As, _Float16* Bs,
                                              int brow, int bcol,
                                              int lane, int wid,
                                              f32x4 acc[4][4]) {
  const int l15 = lane & 15, l4 = lane >> 4;
  const int wr = wid >> 1, wc = wid & 1;
  // staging: each wave moves 2 chunks of 16 rows x 32 cols per tile (lane*16B)
  const int srow = lane >> 2, scol = (lane & 3) * 8;
  const _Float16* Ab = A + (size_t)(brow + srow) * ND + scol;
  const _Float16* Bb = Bw + (size_t)(bcol + srow) * ND + scol;

  for (int kt = 0; kt < ND / 32; ++kt) {
    const int k0 = kt * 32;
#pragma unroll
    for (int c = 0; c < 2; ++c) {
      const int chunk = wid * 2 + c;  // 0..7 -> rows chunk*16..+15
      gload_lds16(Ab + (size_t)chunk * 16 * ND + k0, As + chunk * 512);
      gload_lds16(Bb + (size_t)chunk * 16 * ND + k0, Bs + chunk * 512);
    }
    __syncthreads();  // drains vmcnt (global_load_lds) before reads
    half8 af[4], bf[4];
#pragma unroll
    for (int m = 0; m < 4; ++m)
      af[m] = *(const half8*)(As + (wr * 64 + m * 16 + l15) * 32 + l4 * 8);
#pragma unroll
    for (int n = 0; n < 4; ++n)
      bf[n] = *(const half8*)(Bs + (wc * 64 + n * 16 + l15) * 32 + l4 * 8);
#pragma unroll
    for (int m = 0; m < 4; ++m)
#pragma unroll
      for (int n = 0; n < 4; ++n)
        acc[m][n] = __builtin_amdgcn_mfma_f32_16x16x32_f16(af[m], bf[n],
                                                           acc[m][n], 0, 0, 0);
    __syncthreads();  // protect LDS before next stage
  }
}

// ---------------------------------------------------------------- QKV + RoPE
// mode(blockIdx.z): 0=Q(rope) 1=K(rope) 2=V(transposed store)
// Q/K out: [b*NH+h][s][hd]   Vt out: [b*NH+h][hd][s]
__launch_bounds__(256, 2)
__global__ void qkv_gemm(const _Float16* __restrict__ X,
                         const _Float16* __restrict__ Wq,
                         const _Float16* __restrict__ Wk,
                         const _Float16* __restrict__ Wv,
                         _Float16* __restrict__ Qb,
                         _Float16* __restrict__ Kb,
                         _Float16* __restrict__ Vt,
                         const float* __restrict__ cosT,
                         const float* __restrict__ sinT) {
  __shared__ _Float16 As[128 * 32];
  __shared__ _Float16 Bs[128 * 32];
  const int tid = threadIdx.x, lane = tid & 63, wid = tid >> 6;
  const int l15 = lane & 15, l4 = lane >> 4;
  const int wr = wid >> 1, wc = wid & 1;
  const int brow = blockIdx.y * 128, bcol = blockIdx.x * 128;
  const int mode = blockIdx.z;
  const _Float16* W = (mode == 0) ? Wq : (mode == 1 ? Wk : Wv);

  f32x4 acc[4][4] = {};
  gemm_mainloop(X, W, As, Bs, brow, bcol, lane, wid, acc);

  const int b = brow >> 11;                     // 128-row tile never straddles batch
  const int sbase = (brow & (NS - 1)) + wr * 64;
  const int h = (bcol >> 6) + wc;               // wave's 64 cols == exactly one head

  if (mode < 2) {
    _Float16* oh = ((mode == 0) ? Qb : Kb) + (size_t)(b * NH + h) * NS * NHD;
#pragma unroll
    for (int m = 0; m < 4; ++m) {
#pragma unroll
      for (int r = 0; r < 4; ++r) {
        const int s = sbase + m * 16 + l4 * 4 + r;
#pragma unroll
        for (int n = 0; n < 2; ++n) {          // hd<32 in frags n=0,1; pair at n+2
          const int hd = n * 16 + l15;
          const float c = cosT[s * 32 + hd];
          const float sn = sinT[s * 32 + hd];
          const float lo = acc[m][n][r], hi = acc[m][n + 2][r];
          oh[(size_t)s * NHD + hd]      = (_Float16)(lo * c - hi * sn);
          oh[(size_t)s * NHD + hd + 32] = (_Float16)(hi * c + lo * sn);
        }
      }
    }
  } else {
    // V: store transposed [hd][s]; 4 acc regs = 4 consecutive s -> 8B stores
#pragma unroll
    for (int m = 0; m < 4; ++m) {
      const int s0 = sbase + m * 16 + l4 * 4;
#pragma unroll
      for (int n = 0; n < 4; ++n) {
        const int hd = n * 16 + l15;
        half4 pk;
        pk[0] = (_Float16)acc[m][n][0];
        pk[1] = (_Float16)acc[m][n][1];
        pk[2] = (_Float16)acc[m][n][2];
        pk[3] = (_Float16)acc[m][n][3];
        *(half4*)(Vt + ((size_t)(b * NH + h) * NHD + hd) * NS + s0) = pk;
      }
    }
  }
}

// ---------------------------------------------------------------- flash attn
// grid (qt=0..31, bh=0..31). Block: 4 waves, 64 q-rows (16/wave).
// K tile [64 keys][64 hd] and Vt tile [64 hd][64 keys] in LDS (stride 72).
__launch_bounds__(256, 2)
__global__ void flash_attn(const _Float16* __restrict__ Qb,
                           const _Float16* __restrict__ Kb,
                           const _Float16* __restrict__ Vt,
                           _Float16* __restrict__ Ob) {
  __shared__ _Float16 Ks[64 * 72];
  __shared__ _Float16 Vs[64 * 72];
  __shared__ _Float16 Ps[4][16 * 72];
  const int tid = threadIdx.x, lane = tid & 63, wid = tid >> 6;
  const int l15 = lane & 15, l4 = lane >> 4;
  const int bh = blockIdx.y, qt = blockIdx.x;
  const int qbase = qt * 64 + wid * 16;
  const _Float16* Qh = Qb + (size_t)bh * NS * NHD;
  const _Float16* Kh = Kb + (size_t)bh * NS * NHD;
  const _Float16* Vh = Vt + (size_t)bh * NHD * NS;

  half8 qf[2];  // Q rows held in registers for the whole kernel
#pragma unroll
  for (int kk = 0; kk < 2; ++kk)
    qf[kk] = *(const half8*)&Qh[(size_t)(qbase + l15) * NHD + kk * 32 + l4 * 8];

  f32x4 oacc[4] = {};
  float mrow[4] = {-1e30f, -1e30f, -1e30f, -1e30f};
  float lrow[4] = {0.f, 0.f, 0.f, 0.f};

  const int strow = tid >> 2;        // 0..63
  const int stcol = (tid & 3) * 16;  // 0,16,32,48

  const int nkt = qt + 1;  // causal: only tiles with keys <= q
  for (int kt = 0; kt < nkt; ++kt) {
    {  // stage K and V tiles (32B contiguous per thread, padded LDS)
      const _Float16* ksrc = &Kh[(size_t)(kt * 64 + strow) * NHD + stcol];
      *(half8*)&Ks[strow * 72 + stcol]     = *(const half8*)(ksrc);
      *(half8*)&Ks[strow * 72 + stcol + 8] = *(const half8*)(ksrc + 8);
      const _Float16* vsrc = &Vh[(size_t)strow * NS + kt * 64 + stcol];
      *(half8*)&Vs[strow * 72 + stcol]     = *(const half8*)(vsrc);
      *(half8*)&Vs[strow * 72 + stcol + 8] = *(const half8*)(vsrc + 8);
    }
    __syncthreads();

    // S = Q K^T : 16q x 64k per wave
    f32x4 sacc[4] = {};
#pragma unroll
    for (int kk = 0; kk < 2; ++kk) {
#pragma unroll
      for (int n = 0; n < 4; ++n) {
        half8 kf = *(const half8*)&Ks[(n * 16 + l15) * 72 + kk * 32 + l4 * 8];
        sacc[n] = __builtin_amdgcn_mfma_f32_16x16x32_f16(qf[kk], kf, sacc[n], 0, 0, 0);
      }
    }

    // scale + causal mask + online softmax (wave-parallel over 16-lane groups)
    float pv[4][4];
#pragma unroll
    for (int n = 0; n < 4; ++n) {
      const int key = kt * 64 + n * 16 + l15;
#pragma unroll
      for (int r = 0; r < 4; ++r) {
        const int q = qbase + l4 * 4 + r;
        const float v = sacc[n][r] * 0.125f;
        pv[n][r] = (key > q) ? -1e30f : v;
      }
    }
#pragma unroll
    for (int r = 0; r < 4; ++r) {
      float mx = fmaxf(fmaxf(pv[0][r], pv[1][r]), fmaxf(pv[2][r], pv[3][r]));
#pragma unroll
      for (int off = 1; off < 16; off <<= 1)
        mx = fmaxf(mx, __shfl_xor(mx, off, 64));
      const float mnew = fmaxf(mrow[r], mx);
      const float alpha = __expf(mrow[r] - mnew);
      mrow[r] = mnew;
      float rs = 0.f;
#pragma unroll
      for (int n = 0; n < 4; ++n) {
        const float e = __expf(pv[n][r] - mnew);
        pv[n][r] = e;
        rs += e;
      }
#pragma unroll
      for (int off = 1; off < 16; off <<= 1)
        rs += __shfl_xor(rs, off, 64);
      lrow[r] = lrow[r] * alpha + rs;
#pragma unroll
      for (int n = 0; n < 4; ++n)
        oacc[n][r] *= alpha;
    }

    // P (C-layout) -> LDS -> A-layout for PV
#pragma unroll
    for (int r = 0; r < 4; ++r)
#pragma unroll
      for (int n = 0; n < 4; ++n)
        Ps[wid][(l4 * 4 + r) * 72 + n * 16 + l15] = (_Float16)pv[n][r];
    __syncthreads();

#pragma unroll
    for (int kk = 0; kk < 2; ++kk) {
      half8 pa = *(const half8*)&Ps[wid][l15 * 72 + kk * 32 + l4 * 8];
#pragma unroll
      for (int n = 0; n < 4; ++n) {
        half8 vf = *(const half8*)&Vs[(n * 16 + l15) * 72 + kk * 32 + l4 * 8];
        oacc[n] = __builtin_amdgcn_mfma_f32_16x16x32_f16(pa, vf, oacc[n], 0, 0, 0);
      }
    }
    __syncthreads();
  }

  // epilogue: O/l -> [b][s][h*64+d] f16 for the final projection
  const int b = bh >> 4, h = bh & 15;
  float invl[4];
#pragma unroll
  for (int r = 0; r < 4; ++r) invl[r] = 1.0f / lrow[r];
#pragma unroll
  for (int n = 0; n < 4; ++n) {
    const int d = n * 16 + l15;
#pragma unroll
    for (int r = 0; r < 4; ++r) {
      const int s = qbase + l4 * 4 + r;
      Ob[((size_t)(b * NS + s)) * ND + h * NHD + d] = (_Float16)(oacc[n][r] * invl[r]);
    }
  }
}

// ---------------------------------------------------------------- out proj
__launch_bounds__(256, 2)
__global__ void proj_gemm(const _Float16* __restrict__ A,
                          const _Float16* __restrict__ W,
                          float* __restrict__ out) {
  __shared__ _Float16 As[128 * 32];
  __shared__ _Float16 Bs[128 * 32];
  const int tid = threadIdx.x, lane = tid & 63, wid = tid >> 6;
  const int l15 = lane & 15, l4 = lane >> 4;
  const int wr = wid >> 1, wc = wid & 1;
  const int brow = blockIdx.y * 128, bcol = blockIdx.x * 128;
  f32x4 acc[4][4] = {};
  gemm_mainloop(A, W, As, Bs, brow, bcol, lane, wid, acc);
#pragma unroll
  for (int m = 0; m < 4; ++m)
#pragma unroll
    for (int n = 0; n < 4; ++n)
#pragma unroll
      for (int r = 0; r < 4; ++r)
        out[(size_t)(brow + wr * 64 + m * 16 + l4 * 4 + r) * ND
            + bcol + wc * 64 + n * 16 + l15] = acc[m][n][r];
}

// ---------------------------------------------------------------- launch
extern "C" void kernel_launch(void* const* d_in, const int* in_sizes, int n_in,
                              void* d_out, int out_size, void* d_ws, size_t ws_size,
                              hipStream_t stream) {
  const float* x  = (const float*)d_in[0];
  // d_in[1] = attention_mask: exactly the causal -1e9 triangle -> applied analytically
  const float* wq = (const float*)d_in[2];
  const float* wk = (const float*)d_in[3];
  const float* wv = (const float*)d_in[4];
  const float* wo = (const float*)d_in[5];
  float* out = (float*)d_out;

  char* w = (char*)d_ws;
  _Float16* xb   = (_Float16*)(w);                    // 8 MB  [4096][1024]
  _Float16* wqb  = (_Float16*)(w + (8ull  << 20));    // 2 MB
  _Float16* wkb  = (_Float16*)(w + (10ull << 20));
  _Float16* wvb  = (_Float16*)(w + (12ull << 20));
  _Float16* wob  = (_Float16*)(w + (14ull << 20));
  _Float16* Qb   = (_Float16*)(w + (16ull << 20));    // 8 MB  [32][2048][64]
  _Float16* Kb   = (_Float16*)(w + (24ull << 20));    // 8 MB
  _Float16* Vt   = (_Float16*)(w + (32ull << 20));    // 8 MB  [32][64][2048]
  _Float16* Ob   = (_Float16*)(w + (40ull << 20));    // 8 MB  [4096][1024]
  float*    cosT = (float*)   (w + (48ull << 20));    // 256 KB [2048][32]
  float*    sinT = (float*)   (w + (48ull << 20) + (1ull << 18));

  dim3 blk(256);
  cvt_f32_f16<<<2048, blk, 0, stream>>>(x,  xb,  524288);
  cvt_f32_f16<<<512,  blk, 0, stream>>>(wq, wqb, 131072);
  cvt_f32_f16<<<512,  blk, 0, stream>>>(wk, wkb, 131072);
  cvt_f32_f16<<<512,  blk, 0, stream>>>(wv, wvb, 131072);
  cvt_f32_f16<<<512,  blk, 0, stream>>>(wo, wob, 131072);
  rope_tables<<<256,  blk, 0, stream>>>(cosT, sinT);

  qkv_gemm<<<dim3(8, 32, 3), blk, 0, stream>>>(xb, wqb, wkb, wvb, Qb, Kb, Vt,
                                               cosT, sinT);
  flash_attn<<<dim3(32, 32), blk, 0, stream>>>(Qb, Kb, Vt, Ob);
  proj_gemm<<<dim3(8, 32), blk, 0, stream>>>(Ob, wob, out);
}

// Round 2
// 123.984 us; speedup vs baseline: 1.5626x; 1.5626x over previous
//
#include <hip/hip_runtime.h>
#include <cstdint>
#include <cstddef>

typedef __attribute__((ext_vector_type(8))) _Float16 half8;
typedef __attribute__((ext_vector_type(4))) _Float16 half4;
typedef __attribute__((ext_vector_type(4))) float f32x4;

#define NB 2
#define NS 2048
#define ND 1024
#define NH 16
#define NHD 64
#define NM (NB * NS) /* 4096 */

// ---------------------------------------------------------------- converts
__global__ void cvt_f32_f16(const float* __restrict__ src,
                            _Float16* __restrict__ dst, int n8) {
  int i = blockIdx.x * 256 + threadIdx.x;
  if (i >= n8) return;
  const float4* s4 = (const float4*)src + (size_t)i * 2;
  float4 a = s4[0], b = s4[1];
  half8 h;
  h[0] = (_Float16)a.x; h[1] = (_Float16)a.y;
  h[2] = (_Float16)a.z; h[3] = (_Float16)a.w;
  h[4] = (_Float16)b.x; h[5] = (_Float16)b.y;
  h[6] = (_Float16)b.z; h[7] = (_Float16)b.w;
  *(half8*)(dst + (size_t)i * 8) = h;
}

// cos/sin tables: [s][j], j = freq index 0..31. angle = s * 10000^(-2j/64)
__global__ void rope_tables(float* __restrict__ cosT, float* __restrict__ sinT) {
  int t = blockIdx.x * 256 + threadIdx.x;  // 0..65535
  int s = t >> 5, j = t & 31;
  float inv = expf(-(float)(2 * j) * (9.210340371976184f / 64.0f)); // ln(10000)/64
  float ang = (float)s * inv;
  cosT[t] = cosf(ang);
  sinT[t] = sinf(ang);
}

// ---------------------------------------------------------------- GEMM core
__device__ __forceinline__ void gload_lds16(const void* g, void* lds) {
  __builtin_amdgcn_global_load_lds(
      (const __attribute__((address_space(1))) unsigned int*)g,
      (__attribute__((address_space(3))) unsigned int*)lds, 16, 0, 0);
}

__device__ __forceinline__ float exp2_fast(float x) {
  float r;
  asm("v_exp_f32 %0, %1" : "=v"(r) : "v"(x));
  return r;
}

__device__ __forceinline__ void gemm_mainloop(const _Float16* __restrict__ A,
                                              const _Float16* __restrict__ Bw,
                                              _Float16* As, _Float16* Bs,
                                              int brow, int bcol,
                                              int lane, int wid,
                                              f32x4 acc[4][4]) {
  const int l15 = lane & 15, l4 = lane >> 4;
  const int wr = wid >> 1, wc = wid & 1;
  const int srow = lane >> 2, scol = (lane & 3) * 8;
  const _Float16* Ab = A + (size_t)(brow + srow) * ND + scol;
  const _Float16* Bb = Bw + (size_t)(bcol + srow) * ND + scol;

  for (int kt = 0; kt < ND / 32; ++kt) {
    const int k0 = kt * 32;
#pragma unroll
    for (int c = 0; c < 2; ++c) {
      const int chunk = wid * 2 + c;  // 0..7 -> rows chunk*16..+15
      gload_lds16(Ab + (size_t)chunk * 16 * ND + k0, As + chunk * 512);
      gload_lds16(Bb + (size_t)chunk * 16 * ND + k0, Bs + chunk * 512);
    }
    __syncthreads();
    half8 af[4], bf[4];
#pragma unroll
    for (int m = 0; m < 4; ++m)
      af[m] = *(const half8*)(As + (wr * 64 + m * 16 + l15) * 32 + l4 * 8);
#pragma unroll
    for (int n = 0; n < 4; ++n)
      bf[n] = *(const half8*)(Bs + (wc * 64 + n * 16 + l15) * 32 + l4 * 8);
#pragma unroll
    for (int m = 0; m < 4; ++m)
#pragma unroll
      for (int n = 0; n < 4; ++n)
        acc[m][n] = __builtin_amdgcn_mfma_f32_16x16x32_f16(af[m], bf[n],
                                                           acc[m][n], 0, 0, 0);
    __syncthreads();
  }
}

// ---------------------------------------------------------------- QKV + RoPE
__launch_bounds__(256, 2)
__global__ void qkv_gemm(const _Float16* __restrict__ X,
                         const _Float16* __restrict__ Wq,
                         const _Float16* __restrict__ Wk,
                         const _Float16* __restrict__ Wv,
                         _Float16* __restrict__ Qb,
                         _Float16* __restrict__ Kb,
                         _Float16* __restrict__ Vt,
                         const float* __restrict__ cosT,
                         const float* __restrict__ sinT) {
  __shared__ __align__(16) _Float16 As[128 * 32];
  __shared__ __align__(16) _Float16 Bs[128 * 32];
  const int tid = threadIdx.x, lane = tid & 63, wid = tid >> 6;
  const int l15 = lane & 15, l4 = lane >> 4;
  const int wr = wid >> 1, wc = wid & 1;
  const int brow = blockIdx.y * 128, bcol = blockIdx.x * 128;
  const int mode = blockIdx.z;
  const _Float16* W = (mode == 0) ? Wq : (mode == 1 ? Wk : Wv);

  f32x4 acc[4][4] = {};
  gemm_mainloop(X, W, As, Bs, brow, bcol, lane, wid, acc);

  const int b = brow >> 11;
  const int sbase = (brow & (NS - 1)) + wr * 64;
  const int h = (bcol >> 6) + wc;

  if (mode < 2) {
    _Float16* oh = ((mode == 0) ? Qb : Kb) + (size_t)(b * NH + h) * NS * NHD;
#pragma unroll
    for (int m = 0; m < 4; ++m) {
#pragma unroll
      for (int r = 0; r < 4; ++r) {
        const int s = sbase + m * 16 + l4 * 4 + r;
#pragma unroll
        for (int n = 0; n < 2; ++n) {
          const int hd = n * 16 + l15;
          const float c = cosT[s * 32 + hd];
          const float sn = sinT[s * 32 + hd];
          const float lo = acc[m][n][r], hi = acc[m][n + 2][r];
          oh[(size_t)s * NHD + hd]      = (_Float16)(lo * c - hi * sn);
          oh[(size_t)s * NHD + hd + 32] = (_Float16)(hi * c + lo * sn);
        }
      }
    }
  } else {
#pragma unroll
    for (int m = 0; m < 4; ++m) {
      const int s0 = sbase + m * 16 + l4 * 4;
#pragma unroll
      for (int n = 0; n < 4; ++n) {
        const int hd = n * 16 + l15;
        half4 pk;
        pk[0] = (_Float16)acc[m][n][0];
        pk[1] = (_Float16)acc[m][n][1];
        pk[2] = (_Float16)acc[m][n][2];
        pk[3] = (_Float16)acc[m][n][3];
        *(half4*)(Vt + ((size_t)(b * NH + h) * NHD + hd) * NS + s0) = pk;
      }
    }
  }
}

// ---------------------------------------------------------------- flash attn
// 1D grid: id = (qt<<5) | bh. Block: 4 waves; wave w owns q rows qt*64+w*16..+15.
// Swapped QK^T: lane (l4,l15) holds S[key = n*16+l4*4+r][q = l15] -> row-local
// softmax (2 shfl). P stays in registers and feeds PV's B-operand directly.
// K/V tiles in LDS, double-buffered, XOR-swizzled ((row&7)<<4 on byte addr),
// staged with global_load_lds from inverse-swizzled global addresses.
__launch_bounds__(256, 4)
__global__ void flash_attn(const _Float16* __restrict__ Qb,
                           const _Float16* __restrict__ Kb,
                           const _Float16* __restrict__ Vt,
                           _Float16* __restrict__ Ob) {
  __shared__ __align__(16) _Float16 Ks[2][64 * 64];
  __shared__ __align__(16) _Float16 Vs[2][64 * 64];
  const int tid = threadIdx.x, lane = tid & 63, wid = tid >> 6;
  const int l15 = lane & 15, l4 = lane >> 4;
  const int bh = blockIdx.x & 31, qt = blockIdx.x >> 5;
  const _Float16* Qh = Qb + (size_t)bh * NS * NHD;
  const char* Kg = (const char*)(Kb + (size_t)bh * NS * NHD);
  const char* Vg = (const char*)(Vt + (size_t)bh * NHD * NS);

  // Q B-fragments (q = l15 within this wave's 16-row stripe), held all kernel
  half8 qf[2];
#pragma unroll
  for (int kk = 0; kk < 2; ++kk)
    qf[kk] = *(const half8*)&Qh[(size_t)(qt * 64 + wid * 16 + l15) * NHD + kk * 32 + l4 * 8];

  f32x4 oacc[4] = {};           // O[q=l15][d = n*16 + l4*4 + r]
  float mrun = -3.0e38f, lrun = 0.f;

  // staging geometry: 8 chunks of 1KB per 8KB tile; wave w does chunks 2w,2w+1
  const int swz_lane = ((lane >> 3) & 7) << 4;   // XOR bits 4..6 by row&7
  const int nkt = qt + 1;

  // prologue: stage tile 0 into buf 0
#pragma unroll
  for (int c = 0; c < 2; ++c) {
    const int chunk = wid * 2 + c;
    const int slot = chunk * 1024 + lane * 16;
    const int sw = slot ^ swz_lane;
    gload_lds16(Kg + sw, (char*)&Ks[0][0] + slot);
    const int vrow = slot >> 7;
    gload_lds16(Vg + (size_t)vrow * (NS * 2) + (sw & 127), (char*)&Vs[0][0] + slot);
  }
  __syncthreads();

  int cur = 0;
  const float K1 = 0.125f * 1.4426950408889634f;  // scale * log2(e)
  const int qloc = wid * 16 + l15;                // q local to 64-row block

  for (int kt = 0; kt < nkt; ++kt) {
    // ---- prefetch next tile into cur^1
    if (kt + 1 < nkt) {
      const size_t knext = (size_t)(kt + 1);
#pragma unroll
      for (int c = 0; c < 2; ++c) {
        const int chunk = wid * 2 + c;
        const int slot = chunk * 1024 + lane * 16;
        const int sw = slot ^ swz_lane;
        gload_lds16(Kg + knext * 8192 + sw, (char*)&Ks[cur ^ 1][0] + slot);
        const int vrow = slot >> 7;
        gload_lds16(Vg + (size_t)vrow * (NS * 2) + knext * 128 + (sw & 127),
                    (char*)&Vs[cur ^ 1][0] + slot);
      }
    }

    const bool diag = (kt == qt);
    const char* Kbuf = (const char*)&Ks[cur][0];
    const char* Vbuf = (const char*)&Vs[cur][0];
    const int rswz = (l15 & 7) << 4;

    // ---- S^T = K Q^T : sacc[n] holds S[key = n*16+l4*4+r][q=l15]
    f32x4 sacc[4] = {};
#pragma unroll
    for (int kk = 0; kk < 2; ++kk) {
#pragma unroll
      for (int n = 0; n < 4; ++n) {
        if (diag && n > wid) continue;  // fully-masked key frags
        const int off = ((n * 16 + l15) * 128 + kk * 64 + l4 * 16) ^ rswz;
        half8 kf = *(const half8*)(Kbuf + off);
        sacc[n] = __builtin_amdgcn_mfma_f32_16x16x32_f16(kf, qf[kk], sacc[n], 0, 0, 0);
      }
    }

    // ---- online softmax, fully lane-local (q = l15; keys spread over l4)
    float t[16];
#pragma unroll
    for (int n = 0; n < 4; ++n)
#pragma unroll
      for (int r = 0; r < 4; ++r) {
        float v = sacc[n][r] * K1;
        if (diag) {
          const int ki = n * 16 + l4 * 4 + r;
          v = (ki > qloc) ? -3.0e38f : v;
        }
        t[n * 4 + r] = v;
      }
    float mx = t[0];
#pragma unroll
    for (int j = 1; j < 16; ++j) mx = fmaxf(mx, t[j]);
    mx = fmaxf(mx, __shfl_xor(mx, 16, 64));
    mx = fmaxf(mx, __shfl_xor(mx, 32, 64));
    const float mnew = fmaxf(mrun, mx);
    const float alpha = exp2_fast(mrun - mnew);
    mrun = mnew;
    float ps[16], rs = 0.f;
#pragma unroll
    for (int j = 0; j < 16; ++j) {
      ps[j] = exp2_fast(t[j] - mnew);
      rs += ps[j];
    }
    rs += __shfl_xor(rs, 16, 64);
    rs += __shfl_xor(rs, 32, 64);
    lrun = lrun * alpha + rs;
#pragma unroll
    for (int n = 0; n < 4; ++n) {
      oacc[n][0] *= alpha; oacc[n][1] *= alpha;
      oacc[n][2] *= alpha; oacc[n][3] *= alpha;
    }

    // ---- PV: O^T += V^T P^T. Shared k-map k = c*32 + (j>>2)*16 + l4*4 + (j&3)
#pragma unroll
    for (int c = 0; c < 2; ++c) {
      if (diag && c == 1 && wid < 2) continue;  // keys 32..63 fully masked
      half8 pb;
#pragma unroll
      for (int j = 0; j < 8; ++j)
        pb[j] = (_Float16)ps[(2 * c + (j >> 2)) * 4 + (j & 3)];
#pragma unroll
      for (int n = 0; n < 4; ++n) {
        const int off0 = ((n * 16 + l15) * 128 + c * 64 + l4 * 8) ^ rswz;
        const int off1 = off0 ^ 32;  // +16 keys (bit5 untouched by rswz)
        half4 vlo = *(const half4*)(Vbuf + off0);
        half4 vhi = *(const half4*)(Vbuf + off1);
        half8 va;
        va[0] = vlo[0]; va[1] = vlo[1]; va[2] = vlo[2]; va[3] = vlo[3];
        va[4] = vhi[0]; va[5] = vhi[1]; va[6] = vhi[2]; va[7] = vhi[3];
        oacc[n] = __builtin_amdgcn_mfma_f32_16x16x32_f16(va, pb, oacc[n], 0, 0, 0);
      }
    }

    __syncthreads();  // drains prefetch vmcnt; all waves done with cur
    cur ^= 1;
  }

  // ---- epilogue
  const int b = bh >> 4, h = bh & 15;
  const int s = qt * 64 + wid * 16 + l15;
  const float invl = 1.0f / lrun;
#pragma unroll
  for (int n = 0; n < 4; ++n) {
    half4 o;
    o[0] = (_Float16)(oacc[n][0] * invl);
    o[1] = (_Float16)(oacc[n][1] * invl);
    o[2] = (_Float16)(oacc[n][2] * invl);
    o[3] = (_Float16)(oacc[n][3] * invl);
    *(half4*)&Ob[((size_t)(b * NS + s)) * ND + h * NHD + n * 16 + l4 * 4] = o;
  }
}

// ---------------------------------------------------------------- out proj
__launch_bounds__(256, 2)
__global__ void proj_gemm(const _Float16* __restrict__ A,
                          const _Float16* __restrict__ W,
                          float* __restrict__ out) {
  __shared__ __align__(16) _Float16 As[128 * 32];
  __shared__ __align__(16) _Float16 Bs[128 * 32];
  const int tid = threadIdx.x, lane = tid & 63, wid = tid >> 6;
  const int l15 = lane & 15, l4 = lane >> 4;
  const int wr = wid >> 1, wc = wid & 1;
  const int brow = blockIdx.y * 128, bcol = blockIdx.x * 128;
  f32x4 acc[4][4] = {};
  gemm_mainloop(A, W, As, Bs, brow, bcol, lane, wid, acc);
#pragma unroll
  for (int m = 0; m < 4; ++m)
#pragma unroll
    for (int n = 0; n < 4; ++n)
#pragma unroll
      for (int r = 0; r < 4; ++r)
        out[(size_t)(brow + wr * 64 + m * 16 + l4 * 4 + r) * ND
            + bcol + wc * 64 + n * 16 + l15] = acc[m][n][r];
}

// ---------------------------------------------------------------- launch
extern "C" void kernel_launch(void* const* d_in, const int* in_sizes, int n_in,
                              void* d_out, int out_size, void* d_ws, size_t ws_size,
                              hipStream_t stream) {
  const float* x  = (const float*)d_in[0];
  const float* wq = (const float*)d_in[2];
  const float* wk = (const float*)d_in[3];
  const float* wv = (const float*)d_in[4];
  const float* wo = (const float*)d_in[5];
  float* out = (float*)d_out;

  char* w = (char*)d_ws;
  _Float16* xb   = (_Float16*)(w);                    // 8 MB  [4096][1024]
  _Float16* wqb  = (_Float16*)(w + (8ull  << 20));    // 2 MB
  _Float16* wkb  = (_Float16*)(w + (10ull << 20));
  _Float16* wvb  = (_Float16*)(w + (12ull << 20));
  _Float16* wob  = (_Float16*)(w + (14ull << 20));
  _Float16* Qb   = (_Float16*)(w + (16ull << 20));    // 8 MB  [32][2048][64]
  _Float16* Kb   = (_Float16*)(w + (24ull << 20));    // 8 MB
  _Float16* Vt   = (_Float16*)(w + (32ull << 20));    // 8 MB  [32][64][2048]
  _Float16* Ob   = (_Float16*)(w + (40ull << 20));    // 8 MB  [4096][1024]
  float*    cosT = (float*)   (w + (48ull << 20));    // 256 KB [2048][32]
  float*    sinT = (float*)   (w + (48ull << 20) + (1ull << 18));

  dim3 blk(256);
  cvt_f32_f16<<<2048, blk, 0, stream>>>(x,  xb,  524288);
  cvt_f32_f16<<<512,  blk, 0, stream>>>(wq, wqb, 131072);
  cvt_f32_f16<<<512,  blk, 0, stream>>>(wk, wkb, 131072);
  cvt_f32_f16<<<512,  blk, 0, stream>>>(wv, wvb, 131072);
  cvt_f32_f16<<<512,  blk, 0, stream>>>(wo, wob, 131072);
  rope_tables<<<256,  blk, 0, stream>>>(cosT, sinT);

  qkv_gemm<<<dim3(8, 32, 3), blk, 0, stream>>>(xb, wqb, wkb, wvb, Qb, Kb, Vt,
                                               cosT, sinT);
  flash_attn<<<1024, blk, 0, stream>>>(Qb, Kb, Vt, Ob);
  proj_gemm<<<dim3(8, 32), blk, 0, stream>>>(Ob, wob, out);
}

// Round 5
// 114.957 us; speedup vs baseline: 1.6853x; 1.0785x over previous
//
#include <hip/hip_runtime.h>
#include <cstdint>
#include <cstddef>

typedef __attribute__((ext_vector_type(8))) _Float16 half8;
typedef __attribute__((ext_vector_type(4))) _Float16 half4;
typedef __attribute__((ext_vector_type(4))) float f32x4;

#define NB 2
#define NS 2048
#define ND 1024
#define NH 16
#define NHD 64
#define NM (NB * NS) /* 4096 */

// ---------------------------------------------------------------- prep (fused)
__device__ __forceinline__ void cvt8(const float* __restrict__ s,
                                     _Float16* __restrict__ d, int g) {
  const float4* s4 = (const float4*)s + (size_t)g * 2;
  float4 a = s4[0], b = s4[1];
  half8 h;
  h[0] = (_Float16)a.x; h[1] = (_Float16)a.y;
  h[2] = (_Float16)a.z; h[3] = (_Float16)a.w;
  h[4] = (_Float16)b.x; h[5] = (_Float16)b.y;
  h[6] = (_Float16)b.z; h[7] = (_Float16)b.w;
  *(half8*)(d + (size_t)g * 8) = h;
}

__global__ void prep(const float* __restrict__ x,
                     const float* __restrict__ wq, const float* __restrict__ wk,
                     const float* __restrict__ wv, const float* __restrict__ wo,
                     _Float16* __restrict__ xb,
                     _Float16* __restrict__ wqb, _Float16* __restrict__ wkb,
                     _Float16* __restrict__ wvb, _Float16* __restrict__ wob,
                     float* __restrict__ cosT, float* __restrict__ sinT) {
  int i = blockIdx.x * 256 + threadIdx.x;
  if (i < 524288) {
    cvt8(x, xb, i);
  } else if (i < 1048576) {
    int j = i - 524288;
    int k = j >> 17, g = j & 131071;
    const float* ws = (k == 0) ? wq : (k == 1) ? wk : (k == 2) ? wv : wo;
    _Float16* wd = (k == 0) ? wqb : (k == 1) ? wkb : (k == 2) ? wvb : wob;
    cvt8(ws, wd, g);
  } else if (i < 1056768) {
    int t0 = (i - 1048576) * 8;
#pragma unroll
    for (int e = 0; e < 8; ++e) {
      int t = t0 + e;
      int s = t >> 5, j = t & 31;
      float inv = expf(-(float)(2 * j) * (9.210340371976184f / 64.0f));
      float ang = (float)s * inv;
      cosT[t] = cosf(ang);
      sinT[t] = sinf(ang);
    }
  }
}

// ---------------------------------------------------------------- helpers
__device__ __forceinline__ void gload_lds16(const void* g, void* lds) {
  __builtin_amdgcn_global_load_lds(
      (const __attribute__((address_space(1))) unsigned int*)g,
      (__attribute__((address_space(3))) unsigned int*)lds, 16, 0, 0);
}

__device__ __forceinline__ float exp2_fast(float x) {
  float r;
  asm("v_exp_f32 %0, %1" : "=v"(r) : "v"(x));
  return r;
}

// ---------------------------------------------------------------- GEMM core
__device__ __forceinline__ void gemm_mainloop(const _Float16* __restrict__ A,
                                              const _Float16* __restrict__ Bw,
                                              _Float16* As, _Float16* Bs,
                                              int brow, int bcol,
                                              int lane, int wid,
                                              f32x4 acc[4][4]) {
  const int l15 = lane & 15, l4 = lane >> 4;
  const int wr = wid >> 1, wc = wid & 1;
  const int srow = lane >> 2, scol = (lane & 3) * 8;
  const _Float16* Ab = A + (size_t)(brow + srow) * ND + scol;
  const _Float16* Bb = Bw + (size_t)(bcol + srow) * ND + scol;

  for (int kt = 0; kt < ND / 32; ++kt) {
    const int k0 = kt * 32;
#pragma unroll
    for (int c = 0; c < 2; ++c) {
      const int chunk = wid * 2 + c;
      gload_lds16(Ab + (size_t)chunk * 16 * ND + k0, As + chunk * 512);
      gload_lds16(Bb + (size_t)chunk * 16 * ND + k0, Bs + chunk * 512);
    }
    __syncthreads();
    half8 af[4], bf[4];
#pragma unroll
    for (int m = 0; m < 4; ++m)
      af[m] = *(const half8*)(As + (wr * 64 + m * 16 + l15) * 32 + l4 * 8);
#pragma unroll
    for (int n = 0; n < 4; ++n)
      bf[n] = *(const half8*)(Bs + (wc * 64 + n * 16 + l15) * 32 + l4 * 8);
#pragma unroll
    for (int m = 0; m < 4; ++m)
#pragma unroll
      for (int n = 0; n < 4; ++n)
        acc[m][n] = __builtin_amdgcn_mfma_f32_16x16x32_f16(af[m], bf[n],
                                                           acc[m][n], 0, 0, 0);
    __syncthreads();
  }
}

// ---------------------------------------------------------------- QKV + RoPE
__launch_bounds__(256, 2)
__global__ void qkv_gemm(const _Float16* __restrict__ X,
                         const _Float16* __restrict__ Wq,
                         const _Float16* __restrict__ Wk,
                         const _Float16* __restrict__ Wv,
                         _Float16* __restrict__ Qb,
                         _Float16* __restrict__ Kb,
                         _Float16* __restrict__ Vt,
                         const float* __restrict__ cosT,
                         const float* __restrict__ sinT) {
  __shared__ __align__(16) _Float16 As[128 * 32];
  __shared__ __align__(16) _Float16 Bs[128 * 32];
  const int tid = threadIdx.x, lane = tid & 63, wid = tid >> 6;
  const int l15 = lane & 15, l4 = lane >> 4;
  const int wr = wid >> 1, wc = wid & 1;
  const int brow = blockIdx.y * 128, bcol = blockIdx.x * 128;
  const int mode = blockIdx.z;
  const _Float16* W = (mode == 0) ? Wq : (mode == 1 ? Wk : Wv);

  f32x4 acc[4][4] = {};
  gemm_mainloop(X, W, As, Bs, brow, bcol, lane, wid, acc);

  const int b = brow >> 11;
  const int sbase = (brow & (NS - 1)) + wr * 64;
  const int h = (bcol >> 6) + wc;

  if (mode < 2) {
    _Float16* oh = ((mode == 0) ? Qb : Kb) + (size_t)(b * NH + h) * NS * NHD;
#pragma unroll
    for (int m = 0; m < 4; ++m) {
#pragma unroll
      for (int r = 0; r < 4; ++r) {
        const int s = sbase + m * 16 + l4 * 4 + r;
#pragma unroll
        for (int n = 0; n < 2; ++n) {
          const int hd = n * 16 + l15;
          const float c = cosT[s * 32 + hd];
          const float sn = sinT[s * 32 + hd];
          const float lo = acc[m][n][r], hi = acc[m][n + 2][r];
          oh[(size_t)s * NHD + hd]      = (_Float16)(lo * c - hi * sn);
          oh[(size_t)s * NHD + hd + 32] = (_Float16)(hi * c + lo * sn);
        }
      }
    }
  } else {
#pragma unroll
    for (int m = 0; m < 4; ++m) {
      const int s0 = sbase + m * 16 + l4 * 4;
#pragma unroll
      for (int n = 0; n < 4; ++n) {
        const int hd = n * 16 + l15;
        half4 pk;
        pk[0] = (_Float16)acc[m][n][0];
        pk[1] = (_Float16)acc[m][n][1];
        pk[2] = (_Float16)acc[m][n][2];
        pk[3] = (_Float16)acc[m][n][3];
        *(half4*)(Vt + ((size_t)(b * NH + h) * NHD + hd) * NS + s0) = pk;
      }
    }
  }
}

// ---------------------------------------------------------------- flash attn
// EXACT R2 structure (single chain per block) — the known-passing version —
// plus semantically-neutral s_setprio around the MFMA clusters.
__launch_bounds__(256, 4)
__global__ void flash_attn(const _Float16* __restrict__ Qb,
                           const _Float16* __restrict__ Kb,
                           const _Float16* __restrict__ Vt,
                           _Float16* __restrict__ Ob) {
  __shared__ __align__(16) _Float16 Ks[2][64 * 64];
  __shared__ __align__(16) _Float16 Vs[2][64 * 64];
  const int tid = threadIdx.x, lane = tid & 63, wid = tid >> 6;
  const int l15 = lane & 15, l4 = lane >> 4;
  const int bh = blockIdx.x & 31, qt = blockIdx.x >> 5;
  const _Float16* Qh = Qb + (size_t)bh * NS * NHD;
  const char* Kg = (const char*)(Kb + (size_t)bh * NS * NHD);
  const char* Vg = (const char*)(Vt + (size_t)bh * NHD * NS);

  half8 qf[2];
#pragma unroll
  for (int kk = 0; kk < 2; ++kk)
    qf[kk] = *(const half8*)&Qh[(size_t)(qt * 64 + wid * 16 + l15) * NHD + kk * 32 + l4 * 8];

  f32x4 oacc[4] = {};
  float mrun = -3.0e38f, lrun = 0.f;

  const int swz_lane = ((lane >> 3) & 7) << 4;
  const int nkt = qt + 1;

#pragma unroll
  for (int c = 0; c < 2; ++c) {
    const int chunk = wid * 2 + c;
    const int slot = chunk * 1024 + lane * 16;
    const int sw = slot ^ swz_lane;
    gload_lds16(Kg + sw, (char*)&Ks[0][0] + slot);
    const int vrow = slot >> 7;
    gload_lds16(Vg + (size_t)vrow * (NS * 2) + (sw & 127), (char*)&Vs[0][0] + slot);
  }
  __syncthreads();

  int cur = 0;
  const float K1 = 0.125f * 1.4426950408889634f;  // scale * log2(e)
  const int qloc = wid * 16 + l15;

  for (int kt = 0; kt < nkt; ++kt) {
    if (kt + 1 < nkt) {
      const size_t knext = (size_t)(kt + 1);
#pragma unroll
      for (int c = 0; c < 2; ++c) {
        const int chunk = wid * 2 + c;
        const int slot = chunk * 1024 + lane * 16;
        const int sw = slot ^ swz_lane;
        gload_lds16(Kg + knext * 8192 + sw, (char*)&Ks[cur ^ 1][0] + slot);
        const int vrow = slot >> 7;
        gload_lds16(Vg + (size_t)vrow * (NS * 2) + knext * 128 + (sw & 127),
                    (char*)&Vs[cur ^ 1][0] + slot);
      }
    }

    const bool diag = (kt == qt);
    const char* Kbuf = (const char*)&Ks[cur][0];
    const char* Vbuf = (const char*)&Vs[cur][0];
    const int rswz = (l15 & 7) << 4;

    // ---- S^T = K Q^T
    f32x4 sacc[4] = {};
    __builtin_amdgcn_s_setprio(1);
#pragma unroll
    for (int kk = 0; kk < 2; ++kk) {
#pragma unroll
      for (int n = 0; n < 4; ++n) {
        if (diag && n > wid) continue;
        const int off = ((n * 16 + l15) * 128 + kk * 64 + l4 * 16) ^ rswz;
        half8 kf = *(const half8*)(Kbuf + off);
        sacc[n] = __builtin_amdgcn_mfma_f32_16x16x32_f16(kf, qf[kk], sacc[n], 0, 0, 0);
      }
    }
    __builtin_amdgcn_s_setprio(0);

    // ---- online softmax, lane-local
    float t[16];
#pragma unroll
    for (int n = 0; n < 4; ++n)
#pragma unroll
      for (int r = 0; r < 4; ++r) {
        float v = sacc[n][r] * K1;
        if (diag) {
          const int ki = n * 16 + l4 * 4 + r;
          v = (ki > qloc) ? -3.0e38f : v;
        }
        t[n * 4 + r] = v;
      }
    float mx = t[0];
#pragma unroll
    for (int j = 1; j < 16; ++j) mx = fmaxf(mx, t[j]);
    mx = fmaxf(mx, __shfl_xor(mx, 16, 64));
    mx = fmaxf(mx, __shfl_xor(mx, 32, 64));
    const float mnew = fmaxf(mrun, mx);
    const float alpha = exp2_fast(mrun - mnew);
    mrun = mnew;
    float ps[16], rs = 0.f;
#pragma unroll
    for (int j = 0; j < 16; ++j) {
      ps[j] = exp2_fast(t[j] - mnew);
      rs += ps[j];
    }
    rs += __shfl_xor(rs, 16, 64);
    rs += __shfl_xor(rs, 32, 64);
    lrun = lrun * alpha + rs;
#pragma unroll
    for (int n = 0; n < 4; ++n) {
      oacc[n][0] *= alpha; oacc[n][1] *= alpha;
      oacc[n][2] *= alpha; oacc[n][3] *= alpha;
    }

    // ---- PV
    __builtin_amdgcn_s_setprio(1);
#pragma unroll
    for (int c = 0; c < 2; ++c) {
      if (diag && c == 1 && wid < 2) continue;
      half8 pb;
#pragma unroll
      for (int j = 0; j < 8; ++j)
        pb[j] = (_Float16)ps[(2 * c + (j >> 2)) * 4 + (j & 3)];
#pragma unroll
      for (int n = 0; n < 4; ++n) {
        const int off0 = ((n * 16 + l15) * 128 + c * 64 + l4 * 8) ^ rswz;
        const int off1 = off0 ^ 32;
        half4 vlo = *(const half4*)(Vbuf + off0);
        half4 vhi = *(const half4*)(Vbuf + off1);
        half8 va;
        va[0] = vlo[0]; va[1] = vlo[1]; va[2] = vlo[2]; va[3] = vlo[3];
        va[4] = vhi[0]; va[5] = vhi[1]; va[6] = vhi[2]; va[7] = vhi[3];
        oacc[n] = __builtin_amdgcn_mfma_f32_16x16x32_f16(va, pb, oacc[n], 0, 0, 0);
      }
    }
    __builtin_amdgcn_s_setprio(0);

    __syncthreads();
    cur ^= 1;
  }

  // ---- epilogue
  const int b = bh >> 4, h = bh & 15;
  const int s = qt * 64 + wid * 16 + l15;
  const float invl = 1.0f / lrun;
#pragma unroll
  for (int n = 0; n < 4; ++n) {
    half4 o;
    o[0] = (_Float16)(oacc[n][0] * invl);
    o[1] = (_Float16)(oacc[n][1] * invl);
    o[2] = (_Float16)(oacc[n][2] * invl);
    o[3] = (_Float16)(oacc[n][3] * invl);
    *(half4*)&Ob[((size_t)(b * NS + s)) * ND + h * NHD + n * 16 + l4 * 4] = o;
  }
}

// ---------------------------------------------------------------- out proj
__launch_bounds__(256, 2)
__global__ void proj_gemm(const _Float16* __restrict__ A,
                          const _Float16* __restrict__ W,
                          float* __restrict__ out) {
  __shared__ __align__(16) _Float16 As[128 * 32];
  __shared__ __align__(16) _Float16 Bs[128 * 32];
  const int tid = threadIdx.x, lane = tid & 63, wid = tid >> 6;
  const int l15 = lane & 15, l4 = lane >> 4;
  const int wr = wid >> 1, wc = wid & 1;
  const int brow = blockIdx.y * 128, bcol = blockIdx.x * 128;
  f32x4 acc[4][4] = {};
  gemm_mainloop(A, W, As, Bs, brow, bcol, lane, wid, acc);
#pragma unroll
  for (int m = 0; m < 4; ++m)
#pragma unroll
    for (int n = 0; n < 4; ++n)
#pragma unroll
      for (int r = 0; r < 4; ++r)
        out[(size_t)(brow + wr * 64 + m * 16 + l4 * 4 + r) * ND
            + bcol + wc * 64 + n * 16 + l15] = acc[m][n][r];
}

// ---------------------------------------------------------------- launch
extern "C" void kernel_launch(void* const* d_in, const int* in_sizes, int n_in,
                              void* d_out, int out_size, void* d_ws, size_t ws_size,
                              hipStream_t stream) {
  const float* x  = (const float*)d_in[0];
  const float* wq = (const float*)d_in[2];
  const float* wk = (const float*)d_in[3];
  const float* wv = (const float*)d_in[4];
  const float* wo = (const float*)d_in[5];
  float* out = (float*)d_out;

  char* w = (char*)d_ws;
  _Float16* xb   = (_Float16*)(w);                    // 8 MB  [4096][1024]
  _Float16* wqb  = (_Float16*)(w + (8ull  << 20));    // 2 MB
  _Float16* wkb  = (_Float16*)(w + (10ull << 20));
  _Float16* wvb  = (_Float16*)(w + (12ull << 20));
  _Float16* wob  = (_Float16*)(w + (14ull << 20));
  _Float16* Qb   = (_Float16*)(w + (16ull << 20));    // 8 MB  [32][2048][64]
  _Float16* Kb   = (_Float16*)(w + (24ull << 20));    // 8 MB
  _Float16* Vt   = (_Float16*)(w + (32ull << 20));    // 8 MB  [32][64][2048]
  _Float16* Ob   = (_Float16*)(w + (40ull << 20));    // 8 MB  [4096][1024]
  float*    cosT = (float*)   (w + (48ull << 20));    // 256 KB [2048][32]
  float*    sinT = (float*)   (w + (48ull << 20) + (1ull << 18));

  dim3 blk(256);
  prep<<<4128, blk, 0, stream>>>(x, wq, wk, wv, wo, xb, wqb, wkb, wvb, wob,
                                 cosT, sinT);
  qkv_gemm<<<dim3(8, 32, 3), blk, 0, stream>>>(xb, wqb, wkb, wvb, Qb, Kb, Vt,
                                               cosT, sinT);
  flash_attn<<<1024, blk, 0, stream>>>(Qb, Kb, Vt, Ob);
  proj_gemm<<<dim3(8, 32), blk, 0, stream>>>(Ob, wob, out);
}

// Round 6
// 109.527 us; speedup vs baseline: 1.7688x; 1.0496x over previous
//
#include <hip/hip_runtime.h>
#include <cstdint>
#include <cstddef>

typedef __attribute__((ext_vector_type(8))) _Float16 half8;
typedef __attribute__((ext_vector_type(4))) _Float16 half4;
typedef __attribute__((ext_vector_type(4))) float f32x4;

#define NB 2
#define NS 2048
#define ND 1024
#define NH 16
#define NHD 64
#define NM (NB * NS) /* 4096 */

// ---------------------------------------------------------------- prep (fused)
__device__ __forceinline__ void cvt8(const float* __restrict__ s,
                                     _Float16* __restrict__ d, int g) {
  const float4* s4 = (const float4*)s + (size_t)g * 2;
  float4 a = s4[0], b = s4[1];
  half8 h;
  h[0] = (_Float16)a.x; h[1] = (_Float16)a.y;
  h[2] = (_Float16)a.z; h[3] = (_Float16)a.w;
  h[4] = (_Float16)b.x; h[5] = (_Float16)b.y;
  h[6] = (_Float16)b.z; h[7] = (_Float16)b.w;
  *(half8*)(d + (size_t)g * 8) = h;
}

__global__ void prep(const float* __restrict__ x,
                     const float* __restrict__ wq, const float* __restrict__ wk,
                     const float* __restrict__ wv, const float* __restrict__ wo,
                     _Float16* __restrict__ xb,
                     _Float16* __restrict__ wqb, _Float16* __restrict__ wkb,
                     _Float16* __restrict__ wvb, _Float16* __restrict__ wob,
                     float* __restrict__ cosT, float* __restrict__ sinT) {
  int i = blockIdx.x * 256 + threadIdx.x;
  if (i < 524288) {
    cvt8(x, xb, i);
  } else if (i < 1048576) {
    int j = i - 524288;
    int k = j >> 17, g = j & 131071;
    const float* ws = (k == 0) ? wq : (k == 1) ? wk : (k == 2) ? wv : wo;
    _Float16* wd = (k == 0) ? wqb : (k == 1) ? wkb : (k == 2) ? wvb : wob;
    cvt8(ws, wd, g);
  } else if (i < 1056768) {
    int t0 = (i - 1048576) * 8;
#pragma unroll
    for (int e = 0; e < 8; ++e) {
      int t = t0 + e;
      int s = t >> 5, j = t & 31;
      float inv = expf(-(float)(2 * j) * (9.210340371976184f / 64.0f));
      float ang = (float)s * inv;
      cosT[t] = cosf(ang);
      sinT[t] = sinf(ang);
    }
  }
}

// ---------------------------------------------------------------- helpers
__device__ __forceinline__ void gload_lds16(const void* g, void* lds) {
  __builtin_amdgcn_global_load_lds(
      (const __attribute__((address_space(1))) unsigned int*)g,
      (__attribute__((address_space(3))) unsigned int*)lds, 16, 0, 0);
}

__device__ __forceinline__ float exp2_fast(float x) {
  float r;
  asm("v_exp_f32 %0, %1" : "=v"(r) : "v"(x));
  return r;
}

// ---------------------------------------------------------------- GEMM core
__device__ __forceinline__ void gemm_mainloop(const _Float16* __restrict__ A,
                                              const _Float16* __restrict__ Bw,
                                              _Float16* As, _Float16* Bs,
                                              int brow, int bcol,
                                              int lane, int wid,
                                              f32x4 acc[4][4]) {
  const int l15 = lane & 15, l4 = lane >> 4;
  const int wr = wid >> 1, wc = wid & 1;
  const int srow = lane >> 2, scol = (lane & 3) * 8;
  const _Float16* Ab = A + (size_t)(brow + srow) * ND + scol;
  const _Float16* Bb = Bw + (size_t)(bcol + srow) * ND + scol;

  for (int kt = 0; kt < ND / 32; ++kt) {
    const int k0 = kt * 32;
#pragma unroll
    for (int c = 0; c < 2; ++c) {
      const int chunk = wid * 2 + c;
      gload_lds16(Ab + (size_t)chunk * 16 * ND + k0, As + chunk * 512);
      gload_lds16(Bb + (size_t)chunk * 16 * ND + k0, Bs + chunk * 512);
    }
    __syncthreads();
    half8 af[4], bf[4];
#pragma unroll
    for (int m = 0; m < 4; ++m)
      af[m] = *(const half8*)(As + (wr * 64 + m * 16 + l15) * 32 + l4 * 8);
#pragma unroll
    for (int n = 0; n < 4; ++n)
      bf[n] = *(const half8*)(Bs + (wc * 64 + n * 16 + l15) * 32 + l4 * 8);
#pragma unroll
    for (int m = 0; m < 4; ++m)
#pragma unroll
      for (int n = 0; n < 4; ++n)
        acc[m][n] = __builtin_amdgcn_mfma_f32_16x16x32_f16(af[m], bf[n],
                                                           acc[m][n], 0, 0, 0);
    __syncthreads();
  }
}

// ---------------------------------------------------------------- QKV + RoPE
__launch_bounds__(256, 2)
__global__ void qkv_gemm(const _Float16* __restrict__ X,
                         const _Float16* __restrict__ Wq,
                         const _Float16* __restrict__ Wk,
                         const _Float16* __restrict__ Wv,
                         _Float16* __restrict__ Qb,
                         _Float16* __restrict__ Kb,
                         _Float16* __restrict__ Vt,
                         const float* __restrict__ cosT,
                         const float* __restrict__ sinT) {
  __shared__ __align__(16) _Float16 As[128 * 32];
  __shared__ __align__(16) _Float16 Bs[128 * 32];
  const int tid = threadIdx.x, lane = tid & 63, wid = tid >> 6;
  const int l15 = lane & 15, l4 = lane >> 4;
  const int wr = wid >> 1, wc = wid & 1;
  const int brow = blockIdx.y * 128, bcol = blockIdx.x * 128;
  const int mode = blockIdx.z;
  const _Float16* W = (mode == 0) ? Wq : (mode == 1 ? Wk : Wv);

  f32x4 acc[4][4] = {};
  gemm_mainloop(X, W, As, Bs, brow, bcol, lane, wid, acc);

  const int b = brow >> 11;
  const int sbase = (brow & (NS - 1)) + wr * 64;
  const int h = (bcol >> 6) + wc;

  if (mode < 2) {
    _Float16* oh = ((mode == 0) ? Qb : Kb) + (size_t)(b * NH + h) * NS * NHD;
#pragma unroll
    for (int m = 0; m < 4; ++m) {
#pragma unroll
      for (int r = 0; r < 4; ++r) {
        const int s = sbase + m * 16 + l4 * 4 + r;
#pragma unroll
        for (int n = 0; n < 2; ++n) {
          const int hd = n * 16 + l15;
          const float c = cosT[s * 32 + hd];
          const float sn = sinT[s * 32 + hd];
          const float lo = acc[m][n][r], hi = acc[m][n + 2][r];
          oh[(size_t)s * NHD + hd]      = (_Float16)(lo * c - hi * sn);
          oh[(size_t)s * NHD + hd + 32] = (_Float16)(hi * c + lo * sn);
        }
      }
    }
  } else {
#pragma unroll
    for (int m = 0; m < 4; ++m) {
      const int s0 = sbase + m * 16 + l4 * 4;
#pragma unroll
      for (int n = 0; n < 4; ++n) {
        const int hd = n * 16 + l15;
        half4 pk;
        pk[0] = (_Float16)acc[m][n][0];
        pk[1] = (_Float16)acc[m][n][1];
        pk[2] = (_Float16)acc[m][n][2];
        pk[3] = (_Float16)acc[m][n][3];
        *(half4*)(Vt + ((size_t)(b * NH + h) * NHD + hd) * NS + s0) = pk;
      }
    }
  }
}

// ---------------------------------------------------------------- flash attn
// Uniform-work blocks: block (pr,bh) runs the R2 body twice, sequentially:
// qt = 31-pr then qt = pr  =>  every block does exactly 33 tile-iterations.
// Per-item state fully re-initialized; no cross-item sharing.
__launch_bounds__(256, 4)
__global__ void flash_attn(const _Float16* __restrict__ Qb,
                           const _Float16* __restrict__ Kb,
                           const _Float16* __restrict__ Vt,
                           _Float16* __restrict__ Ob) {
  __shared__ __align__(16) _Float16 Ks[2][64 * 64];
  __shared__ __align__(16) _Float16 Vs[2][64 * 64];
  const int tid = threadIdx.x, lane = tid & 63, wid = tid >> 6;
  const int l15 = lane & 15, l4 = lane >> 4;
  const int bh = blockIdx.x & 31, pr = blockIdx.x >> 5;
  const _Float16* Qh = Qb + (size_t)bh * NS * NHD;
  const char* Kg = (const char*)(Kb + (size_t)bh * NS * NHD);
  const char* Vg = (const char*)(Vt + (size_t)bh * NHD * NS);

  const float K1 = 0.125f * 1.4426950408889634f;  // scale * log2(e)
  const int swz_lane = ((lane >> 3) & 7) << 4;
  const int qloc = wid * 16 + l15;
  const int rswz = (l15 & 7) << 4;
  const int b = bh >> 4, h = bh & 15;

  for (int item = 0; item < 2; ++item) {
    const int qt = item ? pr : 31 - pr;

    half8 qf[2];
#pragma unroll
    for (int kk = 0; kk < 2; ++kk)
      qf[kk] = *(const half8*)&Qh[(size_t)(qt * 64 + wid * 16 + l15) * NHD + kk * 32 + l4 * 8];

    f32x4 oacc[4] = {};
    float mrun = -3.0e38f, lrun = 0.f;
    const int nkt = qt + 1;

    // prologue: stage tile 0 into buf 0
#pragma unroll
    for (int c = 0; c < 2; ++c) {
      const int chunk = wid * 2 + c;
      const int slot = chunk * 1024 + lane * 16;
      const int sw = slot ^ swz_lane;
      gload_lds16(Kg + sw, (char*)&Ks[0][0] + slot);
      const int vrow = slot >> 7;
      gload_lds16(Vg + (size_t)vrow * (NS * 2) + (sw & 127), (char*)&Vs[0][0] + slot);
    }
    __syncthreads();

    int cur = 0;
    for (int kt = 0; kt < nkt; ++kt) {
      if (kt + 1 < nkt) {
        const size_t knext = (size_t)(kt + 1);
#pragma unroll
        for (int c = 0; c < 2; ++c) {
          const int chunk = wid * 2 + c;
          const int slot = chunk * 1024 + lane * 16;
          const int sw = slot ^ swz_lane;
          gload_lds16(Kg + knext * 8192 + sw, (char*)&Ks[cur ^ 1][0] + slot);
          const int vrow = slot >> 7;
          gload_lds16(Vg + (size_t)vrow * (NS * 2) + knext * 128 + (sw & 127),
                      (char*)&Vs[cur ^ 1][0] + slot);
        }
      }

      const bool diag = (kt == qt);
      const char* Kbuf = (const char*)&Ks[cur][0];
      const char* Vbuf = (const char*)&Vs[cur][0];

      // ---- S^T = K Q^T
      f32x4 sacc[4] = {};
      __builtin_amdgcn_s_setprio(1);
#pragma unroll
      for (int kk = 0; kk < 2; ++kk) {
#pragma unroll
        for (int n = 0; n < 4; ++n) {
          if (diag && n > wid) continue;
          const int off = ((n * 16 + l15) * 128 + kk * 64 + l4 * 16) ^ rswz;
          half8 kf = *(const half8*)(Kbuf + off);
          sacc[n] = __builtin_amdgcn_mfma_f32_16x16x32_f16(kf, qf[kk], sacc[n], 0, 0, 0);
        }
      }
      __builtin_amdgcn_s_setprio(0);

      // ---- online softmax, lane-local
      float t[16];
#pragma unroll
      for (int n = 0; n < 4; ++n)
#pragma unroll
        for (int r = 0; r < 4; ++r) {
          float v = sacc[n][r] * K1;
          if (diag) {
            const int ki = n * 16 + l4 * 4 + r;
            v = (ki > qloc) ? -3.0e38f : v;
          }
          t[n * 4 + r] = v;
        }
      float mx = t[0];
#pragma unroll
      for (int j = 1; j < 16; ++j) mx = fmaxf(mx, t[j]);
      mx = fmaxf(mx, __shfl_xor(mx, 16, 64));
      mx = fmaxf(mx, __shfl_xor(mx, 32, 64));
      const float mnew = fmaxf(mrun, mx);
      const float alpha = exp2_fast(mrun - mnew);
      mrun = mnew;
      float ps[16], rs = 0.f;
#pragma unroll
      for (int j = 0; j < 16; ++j) {
        ps[j] = exp2_fast(t[j] - mnew);
        rs += ps[j];
      }
      rs += __shfl_xor(rs, 16, 64);
      rs += __shfl_xor(rs, 32, 64);
      lrun = lrun * alpha + rs;
#pragma unroll
      for (int n = 0; n < 4; ++n) {
        oacc[n][0] *= alpha; oacc[n][1] *= alpha;
        oacc[n][2] *= alpha; oacc[n][3] *= alpha;
      }

      // ---- PV
      __builtin_amdgcn_s_setprio(1);
#pragma unroll
      for (int c = 0; c < 2; ++c) {
        if (diag && c == 1 && wid < 2) continue;
        half8 pb;
#pragma unroll
        for (int j = 0; j < 8; ++j)
          pb[j] = (_Float16)ps[(2 * c + (j >> 2)) * 4 + (j & 3)];
#pragma unroll
        for (int n = 0; n < 4; ++n) {
          const int off0 = ((n * 16 + l15) * 128 + c * 64 + l4 * 8) ^ rswz;
          const int off1 = off0 ^ 32;
          half4 vlo = *(const half4*)(Vbuf + off0);
          half4 vhi = *(const half4*)(Vbuf + off1);
          half8 va;
          va[0] = vlo[0]; va[1] = vlo[1]; va[2] = vlo[2]; va[3] = vlo[3];
          va[4] = vhi[0]; va[5] = vhi[1]; va[6] = vhi[2]; va[7] = vhi[3];
          oacc[n] = __builtin_amdgcn_mfma_f32_16x16x32_f16(va, pb, oacc[n], 0, 0, 0);
        }
      }
      __builtin_amdgcn_s_setprio(0);

      __syncthreads();
      cur ^= 1;
    }

    // ---- epilogue (registers + global only; no LDS)
    const int s = qt * 64 + wid * 16 + l15;
    const float invl = 1.0f / lrun;
#pragma unroll
    for (int n = 0; n < 4; ++n) {
      half4 o;
      o[0] = (_Float16)(oacc[n][0] * invl);
      o[1] = (_Float16)(oacc[n][1] * invl);
      o[2] = (_Float16)(oacc[n][2] * invl);
      o[3] = (_Float16)(oacc[n][3] * invl);
      *(half4*)&Ob[((size_t)(b * NS + s)) * ND + h * NHD + n * 16 + l4 * 4] = o;
    }
  }
}

// ---------------------------------------------------------------- out proj
__launch_bounds__(256, 2)
__global__ void proj_gemm(const _Float16* __restrict__ A,
                          const _Float16* __restrict__ W,
                          float* __restrict__ out) {
  __shared__ __align__(16) _Float16 As[128 * 32];
  __shared__ __align__(16) _Float16 Bs[128 * 32];
  const int tid = threadIdx.x, lane = tid & 63, wid = tid >> 6;
  const int l15 = lane & 15, l4 = lane >> 4;
  const int wr = wid >> 1, wc = wid & 1;
  const int brow = blockIdx.y * 128, bcol = blockIdx.x * 128;
  f32x4 acc[4][4] = {};
  gemm_mainloop(A, W, As, Bs, brow, bcol, lane, wid, acc);
#pragma unroll
  for (int m = 0; m < 4; ++m)
#pragma unroll
    for (int n = 0; n < 4; ++n)
#pragma unroll
      for (int r = 0; r < 4; ++r)
        out[(size_t)(brow + wr * 64 + m * 16 + l4 * 4 + r) * ND
            + bcol + wc * 64 + n * 16 + l15] = acc[m][n][r];
}

// ---------------------------------------------------------------- launch
extern "C" void kernel_launch(void* const* d_in, const int* in_sizes, int n_in,
                              void* d_out, int out_size, void* d_ws, size_t ws_size,
                              hipStream_t stream) {
  const float* x  = (const float*)d_in[0];
  const float* wq = (const float*)d_in[2];
  const float* wk = (const float*)d_in[3];
  const float* wv = (const float*)d_in[4];
  const float* wo = (const float*)d_in[5];
  float* out = (float*)d_out;

  char* w = (char*)d_ws;
  _Float16* xb   = (_Float16*)(w);                    // 8 MB  [4096][1024]
  _Float16* wqb  = (_Float16*)(w + (8ull  << 20));    // 2 MB
  _Float16* wkb  = (_Float16*)(w + (10ull << 20));
  _Float16* wvb  = (_Float16*)(w + (12ull << 20));
  _Float16* wob  = (_Float16*)(w + (14ull << 20));
  _Float16* Qb   = (_Float16*)(w + (16ull << 20));    // 8 MB  [32][2048][64]
  _Float16* Kb   = (_Float16*)(w + (24ull << 20));    // 8 MB
  _Float16* Vt   = (_Float16*)(w + (32ull << 20));    // 8 MB  [32][64][2048]
  _Float16* Ob   = (_Float16*)(w + (40ull << 20));    // 8 MB  [4096][1024]
  float*    cosT = (float*)   (w + (48ull << 20));    // 256 KB [2048][32]
  float*    sinT = (float*)   (w + (48ull << 20) + (1ull << 18));

  dim3 blk(256);
  prep<<<4128, blk, 0, stream>>>(x, wq, wk, wv, wo, xb, wqb, wkb, wvb, wob,
                                 cosT, sinT);
  qkv_gemm<<<dim3(8, 32, 3), blk, 0, stream>>>(xb, wqb, wkb, wvb, Qb, Kb, Vt,
                                               cosT, sinT);
  flash_attn<<<512, blk, 0, stream>>>(Qb, Kb, Vt, Ob);
  proj_gemm<<<dim3(8, 32), blk, 0, stream>>>(Ob, wob, out);
}